// Round 5
// baseline (353.658 us; speedup 1.0000x reference)
//
#include <hip/hip_runtime.h>
#include <math.h>

#define NEG_SLOPE 0.2f

// K1: w_dst[d] = sum_h W_dst[d,h] * a_dst[h]   (1 block, 128 threads)
__global__ void k_wdst(const float* __restrict__ Wd, const float* __restrict__ ad,
                       float* __restrict__ wdst) {
    int d = threadIdx.x;
    float s = 0.f;
    #pragma unroll 8
    for (int h = 0; h < 128; ++h) s += Wd[d * 128 + h] * ad[h];
    wdst[d] = s;
}

// K2: out[row] = dot(X[row,0:128], v). 2 rows per wave, float4/lane, coalesced.
__global__ void k_rowdot(const float* __restrict__ X, const float* __restrict__ v,
                         float* __restrict__ out, int n) {
    int gw = (int)((blockIdx.x * blockDim.x + threadIdx.x) >> 6);
    int lane = threadIdx.x & 63;
    int half = lane >> 5, li = lane & 31;
    int row = gw * 2 + half;
    if (row >= n) return;
    const float4* X4 = (const float4*)X;
    const float4* V4 = (const float4*)v;
    float4 x = X4[(size_t)row * 32 + li];
    float4 b = V4[li];
    float p = x.x * b.x + x.y * b.y + x.z * b.z + x.w * b.w;
    #pragma unroll
    for (int off = 16; off; off >>= 1) p += __shfl_xor(p, off);
    if (li == 0) out[row] = p;
}

// K3: H = X @ W  (X: nrows x 128, W: 128 x 128). 32 rows/block, 4x4 register tile.
__global__ __launch_bounds__(256) void k_hsrc(const float* __restrict__ X,
                                              const float* __restrict__ W,
                                              float* __restrict__ H, int nrows) {
    __shared__ float Xs[32][128];
    int t = threadIdx.x;
    int row0 = blockIdx.x * 32;
    #pragma unroll
    for (int i = 0; i < 16; ++i) {
        int idx = t + i * 256;
        int r = idx >> 7;
        Xs[r][idx & 127] = (row0 + r < nrows) ? X[(size_t)row0 * 128 + idx] : 0.f;
    }
    __syncthreads();
    int cg = t & 31, rg = t >> 5;
    float acc[4][4];
    #pragma unroll
    for (int i = 0; i < 4; ++i)
        #pragma unroll
        for (int j = 0; j < 4; ++j) acc[i][j] = 0.f;
    const float4* W4 = (const float4*)W;
    #pragma unroll 4
    for (int d = 0; d < 128; ++d) {
        float4 wv = W4[d * 32 + cg];
        float x0 = Xs[rg * 4 + 0][d], x1 = Xs[rg * 4 + 1][d];
        float x2 = Xs[rg * 4 + 2][d], x3 = Xs[rg * 4 + 3][d];
        acc[0][0] += x0 * wv.x; acc[0][1] += x0 * wv.y; acc[0][2] += x0 * wv.z; acc[0][3] += x0 * wv.w;
        acc[1][0] += x1 * wv.x; acc[1][1] += x1 * wv.y; acc[1][2] += x1 * wv.z; acc[1][3] += x1 * wv.w;
        acc[2][0] += x2 * wv.x; acc[2][1] += x2 * wv.y; acc[2][2] += x2 * wv.z; acc[2][3] += x2 * wv.w;
        acc[3][0] += x3 * wv.x; acc[3][1] += x3 * wv.y; acc[3][2] += x3 * wv.z; acc[3][3] += x3 * wv.w;
    }
    #pragma unroll
    for (int i = 0; i < 4; ++i) {
        int gr = row0 + rg * 4 + i;
        if (gr < nrows) {
            float4 o = make_float4(acc[i][0], acc[i][1], acc[i][2], acc[i][3]);
            *(float4*)&H[(size_t)gr * 128 + cg * 4] = o;
        }
    }
}

// K4a: degree histogram of dst
__global__ void k_deg(const int* __restrict__ dst, int* __restrict__ deg, int E) {
    int i = blockIdx.x * blockDim.x + threadIdx.x;
    if (i < E) atomicAdd(&deg[dst[i]], 1);
}

// K4b: per-1024-chunk block sums
__global__ __launch_bounds__(256) void k_scanA(const int* __restrict__ deg,
                                               int* __restrict__ bsum, int n) {
    __shared__ int sd[256];
    int t = threadIdx.x;
    int base = blockIdx.x * 1024 + t * 4;
    int s = 0;
    #pragma unroll
    for (int i = 0; i < 4; ++i) if (base + i < n) s += deg[base + i];
    sd[t] = s;
    __syncthreads();
    for (int off = 128; off; off >>= 1) {
        if (t < off) sd[t] += sd[t + off];
        __syncthreads();
    }
    if (t == 0) bsum[blockIdx.x] = sd[0];
}

// K4c: parallel exclusive scan of block sums
__global__ __launch_bounds__(128) void k_scanB(int* __restrict__ bsum, int nb,
                                               int* __restrict__ rowptr, int n, int E) {
    __shared__ int ss[128];
    int t = threadIdx.x;
    if (nb <= 128) {
        int v = (t < nb) ? bsum[t] : 0;
        ss[t] = v;
        __syncthreads();
        for (int off = 1; off < 128; off <<= 1) {
            int u = (t >= off) ? ss[t - off] : 0;
            __syncthreads();
            ss[t] += u;
            __syncthreads();
        }
        if (t < nb) bsum[t] = ss[t] - v;
    } else if (t == 0) {
        int run = 0;
        for (int i = 0; i < nb; ++i) { int v = bsum[i]; bsum[i] = run; run += v; }
    }
    if (t == 0) rowptr[n] = E;
}

// K4d: write exclusive prefix per element
__global__ __launch_bounds__(256) void k_scanC(const int* __restrict__ deg,
                                               const int* __restrict__ bsum,
                                               int* __restrict__ rowptr, int n) {
    __shared__ int ss[256];
    int t = threadIdx.x;
    int base = blockIdx.x * 1024 + t * 4;
    int d[4]; int tsum = 0;
    #pragma unroll
    for (int i = 0; i < 4; ++i) { d[i] = (base + i < n) ? deg[base + i] : 0; tsum += d[i]; }
    ss[t] = tsum;
    __syncthreads();
    for (int off = 1; off < 256; off <<= 1) {
        int v = (t >= off) ? ss[t - off] : 0;
        __syncthreads();
        ss[t] += v;
        __syncthreads();
    }
    int excl = ss[t] - tsum + bsum[blockIdx.x];
    #pragma unroll
    for (int i = 0; i < 4; ++i) {
        if (base + i < n) rowptr[base + i] = excl;
        excl += d[i];
    }
}

// K5: compute ex = exp(leaky(e)) (max-free softmax numerator), pack (src, ex)
__global__ void k_scatter(const int* __restrict__ src, const int* __restrict__ dst,
                          const float* __restrict__ ssrc, const float* __restrict__ sdst,
                          const int* __restrict__ rowptr, int* __restrict__ cursor,
                          int2* __restrict__ csr_pair, int E) {
    int i = blockIdx.x * blockDim.x + threadIdx.x;
    if (i >= E) return;
    int s = src[i], d = dst[i];
    float e = ssrc[s] + sdst[d];
    e = e > 0.f ? e : NEG_SLOPE * e;
    float ex = __expf(e);
    int pos = rowptr[d] + atomicAdd(&cursor[d], 1);
    csr_pair[pos] = make_int2(s, __float_as_int(ex));
}

// K6: gather+accumulate. 4 rows per wave (16 lanes/row, float4 x2 per lane),
// batch-4 edges (8 float4 gathers in flight/lane). G[row,:] = relu(acc/denom + b_al).
__global__ __launch_bounds__(256) void k_gat(
    const int* __restrict__ rowptr, const int2* __restrict__ csr_pair,
    const float* __restrict__ H, const float* __restrict__ b_al,
    float* __restrict__ G, int n) {
    int t = threadIdx.x;
    int wave = t >> 6, lane = t & 63;
    int grp = lane >> 4, gl = lane & 15;
    int row = blockIdx.x * 16 + wave * 4 + grp;
    if (row >= n) return;
    int beg = rowptr[row], end = rowptr[row + 1];
    const float4* H4 = (const float4*)H;
    float4 aA = make_float4(0.f, 0.f, 0.f, 0.f);
    float4 aB = make_float4(0.f, 0.f, 0.f, 0.f);
    float denom = 0.f;
    int j = beg;
    for (; j + 4 <= end; j += 4) {
        int2 p0 = csr_pair[j], p1 = csr_pair[j + 1];
        int2 p2 = csr_pair[j + 2], p3 = csr_pair[j + 3];
        float x0 = __int_as_float(p0.y), x1 = __int_as_float(p1.y);
        float x2 = __int_as_float(p2.y), x3 = __int_as_float(p3.y);
        const float4* b0 = H4 + (size_t)p0.x * 32;
        const float4* b1 = H4 + (size_t)p1.x * 32;
        const float4* b2 = H4 + (size_t)p2.x * 32;
        const float4* b3 = H4 + (size_t)p3.x * 32;
        float4 h0a = b0[gl], h0b = b0[16 + gl];
        float4 h1a = b1[gl], h1b = b1[16 + gl];
        float4 h2a = b2[gl], h2b = b2[16 + gl];
        float4 h3a = b3[gl], h3b = b3[16 + gl];
        denom += (x0 + x1) + (x2 + x3);
        aA.x += x0 * h0a.x + x1 * h1a.x + x2 * h2a.x + x3 * h3a.x;
        aA.y += x0 * h0a.y + x1 * h1a.y + x2 * h2a.y + x3 * h3a.y;
        aA.z += x0 * h0a.z + x1 * h1a.z + x2 * h2a.z + x3 * h3a.z;
        aA.w += x0 * h0a.w + x1 * h1a.w + x2 * h2a.w + x3 * h3a.w;
        aB.x += x0 * h0b.x + x1 * h1b.x + x2 * h2b.x + x3 * h3b.x;
        aB.y += x0 * h0b.y + x1 * h1b.y + x2 * h2b.y + x3 * h3b.y;
        aB.z += x0 * h0b.z + x1 * h1b.z + x2 * h2b.z + x3 * h3b.z;
        aB.w += x0 * h0b.w + x1 * h1b.w + x2 * h2b.w + x3 * h3b.w;
    }
    for (; j + 2 <= end; j += 2) {
        int2 p0 = csr_pair[j], p1 = csr_pair[j + 1];
        float x0 = __int_as_float(p0.y), x1 = __int_as_float(p1.y);
        const float4* b0 = H4 + (size_t)p0.x * 32;
        const float4* b1 = H4 + (size_t)p1.x * 32;
        float4 h0a = b0[gl], h0b = b0[16 + gl];
        float4 h1a = b1[gl], h1b = b1[16 + gl];
        denom += x0 + x1;
        aA.x += x0 * h0a.x + x1 * h1a.x; aA.y += x0 * h0a.y + x1 * h1a.y;
        aA.z += x0 * h0a.z + x1 * h1a.z; aA.w += x0 * h0a.w + x1 * h1a.w;
        aB.x += x0 * h0b.x + x1 * h1b.x; aB.y += x0 * h0b.y + x1 * h1b.y;
        aB.z += x0 * h0b.z + x1 * h1b.z; aB.w += x0 * h0b.w + x1 * h1b.w;
    }
    if (j < end) {
        int2 p0 = csr_pair[j];
        float x0 = __int_as_float(p0.y);
        const float4* b0 = H4 + (size_t)p0.x * 32;
        float4 h0a = b0[gl], h0b = b0[16 + gl];
        denom += x0;
        aA.x += x0 * h0a.x; aA.y += x0 * h0a.y; aA.z += x0 * h0a.z; aA.w += x0 * h0a.w;
        aB.x += x0 * h0b.x; aB.y += x0 * h0b.y; aB.z += x0 * h0b.z; aB.w += x0 * h0b.w;
    }
    float inv = denom > 0.f ? 1.f / denom : 0.f;
    const float4* B4 = (const float4*)b_al;
    float4 bA = B4[gl], bB = B4[16 + gl];
    float4 gA, gB;
    gA.x = fmaxf(aA.x * inv + bA.x, 0.f); gA.y = fmaxf(aA.y * inv + bA.y, 0.f);
    gA.z = fmaxf(aA.z * inv + bA.z, 0.f); gA.w = fmaxf(aA.w * inv + bA.w, 0.f);
    gB.x = fmaxf(aB.x * inv + bB.x, 0.f); gB.y = fmaxf(aB.y * inv + bB.y, 0.f);
    gB.z = fmaxf(aB.z * inv + bB.z, 0.f); gB.w = fmaxf(aB.w * inv + bB.w, 0.f);
    float4* G4 = (float4*)G;
    G4[(size_t)row * 32 + gl] = gA;
    G4[(size_t)row * 32 + 16 + gl] = gB;
}

// K7: out = G @ W_lin + b_lin.  8 rows per wave: per 4-k step, 4 ds_read_b32 of
// W_lin (reused by 8 rows) + 8 uniform float4 G loads + 32 FMA.
__global__ __launch_bounds__(256) void k_out(const float* __restrict__ G,
                                             const float* __restrict__ Wlin,
                                             const float* __restrict__ b_lin,
                                             float* __restrict__ out, int n) {
    __shared__ float Wls[128 * 64];
    int t = threadIdx.x;
    #pragma unroll
    for (int i = 0; i < 32; ++i) Wls[t + i * 256] = Wlin[t + i * 256];
    __syncthreads();
    int wave = t >> 6, lane = t & 63;
    float bl = b_lin[lane];
    const float4* G4 = (const float4*)G;
    int base = (blockIdx.x * 4 + wave) * 8;
    if (base >= n) return;
    float acc[8];
    #pragma unroll
    for (int r = 0; r < 8; ++r) acc[r] = bl;
    if (base + 8 <= n) {
        #pragma unroll 4
        for (int kk = 0; kk < 32; ++kk) {
            float w0 = Wls[(4 * kk + 0) * 64 + lane];
            float w1 = Wls[(4 * kk + 1) * 64 + lane];
            float w2 = Wls[(4 * kk + 2) * 64 + lane];
            float w3 = Wls[(4 * kk + 3) * 64 + lane];
            #pragma unroll
            for (int r = 0; r < 8; ++r) {
                float4 g = G4[(size_t)(base + r) * 32 + kk];
                acc[r] += g.x * w0 + g.y * w1 + g.z * w2 + g.w * w3;
            }
        }
        #pragma unroll
        for (int r = 0; r < 8; ++r)
            out[(size_t)(base + r) * 64 + lane] = acc[r];
    } else {
        for (int kk = 0; kk < 32; ++kk) {
            float w0 = Wls[(4 * kk + 0) * 64 + lane];
            float w1 = Wls[(4 * kk + 1) * 64 + lane];
            float w2 = Wls[(4 * kk + 2) * 64 + lane];
            float w3 = Wls[(4 * kk + 3) * 64 + lane];
            for (int r = 0; r < 8; ++r) {
                if (base + r < n) {
                    float4 g = G4[(size_t)(base + r) * 32 + kk];
                    acc[r] += g.x * w0 + g.y * w1 + g.z * w2 + g.w * w3;
                }
            }
        }
        for (int r = 0; r < 8; ++r)
            if (base + r < n) out[(size_t)(base + r) * 64 + lane] = acc[r];
    }
}

extern "C" void kernel_launch(void* const* d_in, const int* in_sizes, int n_in,
                              void* d_out, int out_size, void* d_ws, size_t ws_size,
                              hipStream_t stream) {
    const float* x_label  = (const float*)d_in[0];
    const float* x_attr   = (const float*)d_in[1];
    const float* W_src_al = (const float*)d_in[7];
    const float* W_dst_al = (const float*)d_in[8];
    const float* a_src_al = (const float*)d_in[9];
    const float* a_dst_al = (const float*)d_in[10];
    const float* b_al     = (const float*)d_in[11];
    const float* W_lin    = (const float*)d_in[12];
    const float* b_lin    = (const float*)d_in[13];
    const int* edge_src   = (const int*)d_in[16];
    const int* edge_dst   = (const int*)d_in[17];

    const int D = 128;
    const int N_L = in_sizes[0] / D;
    const int N_A = in_sizes[1] / D;
    const int E   = in_sizes[16];
    const int nb  = (N_L + 1023) / 1024;

    // workspace layout (floats; keep csr_pair 8B-aligned: all offsets even)
    float* ws = (float*)d_ws;
    float* h_src = ws;                                  // N_A*128
    float* s_src = h_src + (size_t)N_A * 128;           // N_A
    float* s_dst = s_src + N_A;                         // N_L
    float* wdst  = s_dst + N_L;                         // 128
    int*   deg    = (int*)(wdst + 128);                 // N_L
    int*   cursor = deg + N_L;                          // N_L
    int*   rowptr = cursor + N_L;                       // N_L + 2 (pad, even)
    int*   bsum   = rowptr + N_L + 2;                   // 128
    int2*  csr_pair = (int2*)(bsum + 128);              // E (8B each)
    float* G = (float*)(csr_pair + E);                  // N_L*128
    float* out = (float*)d_out;

    hipMemsetAsync(deg, 0, (size_t)2 * N_L * sizeof(int), stream);  // deg + cursor

    // scalar projections
    k_wdst<<<1, 128, 0, stream>>>(W_dst_al, a_dst_al, wdst);
    k_rowdot<<<(N_L + 7) / 8, 256, 0, stream>>>(x_label, wdst, s_dst, N_L);
    // h_src GEMM + its scalar projection
    k_hsrc<<<(N_A + 31) / 32, 256, 0, stream>>>(x_attr, W_src_al, h_src, N_A);
    k_rowdot<<<(N_A + 7) / 8, 256, 0, stream>>>(h_src, a_src_al, s_src, N_A);
    // CSR build (ex precomputed at scatter)
    k_deg<<<(E + 255) / 256, 256, 0, stream>>>(edge_dst, deg, E);
    k_scanA<<<nb, 256, 0, stream>>>(deg, bsum, N_L);
    k_scanB<<<1, 128, 0, stream>>>(bsum, nb, rowptr, N_L, E);
    k_scanC<<<nb, 256, 0, stream>>>(deg, bsum, rowptr, N_L);
    k_scatter<<<(E + 255) / 256, 256, 0, stream>>>(edge_src, edge_dst, s_src, s_dst,
                                                   rowptr, cursor, csr_pair, E);
    // gather + normalize + bias + relu -> G
    k_gat<<<(N_L + 15) / 16, 256, 0, stream>>>(rowptr, csr_pair, h_src, b_al, G, N_L);
    // final GEMM (8 rows/wave)
    k_out<<<(N_L + 31) / 32, 256, 0, stream>>>(G, W_lin, b_lin, out, N_L);
}

// Round 6
// 268.696 us; speedup vs baseline: 1.3162x; 1.3162x over previous
//
#include <hip/hip_runtime.h>
#include <math.h>

#define NEG_SLOPE 0.2f

typedef __attribute__((ext_vector_type(8))) short bf16x8;
typedef __attribute__((ext_vector_type(4))) float f32x4;

// float -> bf16 bits, round-to-nearest-even
__device__ __forceinline__ unsigned short f2bf(float f) {
    unsigned u = __float_as_uint(f);
    unsigned r = (u + 0x7FFFu + ((u >> 16) & 1u)) >> 16;
    return (unsigned short)r;
}

// K1: w_dst[d] = sum_h W_dst[d,h] * a_dst[h]   (1 block, 128 threads)
__global__ void k_wdst(const float* __restrict__ Wd, const float* __restrict__ ad,
                       float* __restrict__ wdst) {
    int d = threadIdx.x;
    float s = 0.f;
    #pragma unroll 8
    for (int h = 0; h < 128; ++h) s += Wd[d * 128 + h] * ad[h];
    wdst[d] = s;
}

// K2: out[row] = dot(X[row,0:128], v). 2 rows per wave, float4/lane, coalesced.
__global__ void k_rowdot(const float* __restrict__ X, const float* __restrict__ v,
                         float* __restrict__ out, int n) {
    int gw = (int)((blockIdx.x * blockDim.x + threadIdx.x) >> 6);
    int lane = threadIdx.x & 63;
    int half = lane >> 5, li = lane & 31;
    int row = gw * 2 + half;
    if (row >= n) return;
    const float4* X4 = (const float4*)X;
    const float4* V4 = (const float4*)v;
    float4 x = X4[(size_t)row * 32 + li];
    float4 b = V4[li];
    float p = x.x * b.x + x.y * b.y + x.z * b.z + x.w * b.w;
    #pragma unroll
    for (int off = 16; off; off >>= 1) p += __shfl_xor(p, off);
    if (li == 0) out[row] = p;
}

// K3: H = X @ W  (X: nrows x 128, W: 128 x 128). 32 rows/block, 4x4 register tile.
__global__ __launch_bounds__(256) void k_hsrc(const float* __restrict__ X,
                                              const float* __restrict__ W,
                                              float* __restrict__ H, int nrows) {
    __shared__ float Xs[32][128];
    int t = threadIdx.x;
    int row0 = blockIdx.x * 32;
    #pragma unroll
    for (int i = 0; i < 16; ++i) {
        int idx = t + i * 256;
        int r = idx >> 7;
        Xs[r][idx & 127] = (row0 + r < nrows) ? X[(size_t)row0 * 128 + idx] : 0.f;
    }
    __syncthreads();
    int cg = t & 31, rg = t >> 5;
    float acc[4][4];
    #pragma unroll
    for (int i = 0; i < 4; ++i)
        #pragma unroll
        for (int j = 0; j < 4; ++j) acc[i][j] = 0.f;
    const float4* W4 = (const float4*)W;
    #pragma unroll 4
    for (int d = 0; d < 128; ++d) {
        float4 wv = W4[d * 32 + cg];
        float x0 = Xs[rg * 4 + 0][d], x1 = Xs[rg * 4 + 1][d];
        float x2 = Xs[rg * 4 + 2][d], x3 = Xs[rg * 4 + 3][d];
        acc[0][0] += x0 * wv.x; acc[0][1] += x0 * wv.y; acc[0][2] += x0 * wv.z; acc[0][3] += x0 * wv.w;
        acc[1][0] += x1 * wv.x; acc[1][1] += x1 * wv.y; acc[1][2] += x1 * wv.z; acc[1][3] += x1 * wv.w;
        acc[2][0] += x2 * wv.x; acc[2][1] += x2 * wv.y; acc[2][2] += x2 * wv.z; acc[2][3] += x2 * wv.w;
        acc[3][0] += x3 * wv.x; acc[3][1] += x3 * wv.y; acc[3][2] += x3 * wv.z; acc[3][3] += x3 * wv.w;
    }
    #pragma unroll
    for (int i = 0; i < 4; ++i) {
        int gr = row0 + rg * 4 + i;
        if (gr < nrows) {
            float4 o = make_float4(acc[i][0], acc[i][1], acc[i][2], acc[i][3]);
            *(float4*)&H[(size_t)gr * 128 + cg * 4] = o;
        }
    }
}

// K4a: degree histogram of dst
__global__ void k_deg(const int* __restrict__ dst, int* __restrict__ deg, int E) {
    int i = blockIdx.x * blockDim.x + threadIdx.x;
    if (i < E) atomicAdd(&deg[dst[i]], 1);
}

// K4b: per-1024-chunk block sums
__global__ __launch_bounds__(256) void k_scanA(const int* __restrict__ deg,
                                               int* __restrict__ bsum, int n) {
    __shared__ int sd[256];
    int t = threadIdx.x;
    int base = blockIdx.x * 1024 + t * 4;
    int s = 0;
    #pragma unroll
    for (int i = 0; i < 4; ++i) if (base + i < n) s += deg[base + i];
    sd[t] = s;
    __syncthreads();
    for (int off = 128; off; off >>= 1) {
        if (t < off) sd[t] += sd[t + off];
        __syncthreads();
    }
    if (t == 0) bsum[blockIdx.x] = sd[0];
}

// K4c: parallel exclusive scan of block sums
__global__ __launch_bounds__(128) void k_scanB(int* __restrict__ bsum, int nb,
                                               int* __restrict__ rowptr, int n, int E) {
    __shared__ int ss[128];
    int t = threadIdx.x;
    if (nb <= 128) {
        int v = (t < nb) ? bsum[t] : 0;
        ss[t] = v;
        __syncthreads();
        for (int off = 1; off < 128; off <<= 1) {
            int u = (t >= off) ? ss[t - off] : 0;
            __syncthreads();
            ss[t] += u;
            __syncthreads();
        }
        if (t < nb) bsum[t] = ss[t] - v;
    } else if (t == 0) {
        int run = 0;
        for (int i = 0; i < nb; ++i) { int v = bsum[i]; bsum[i] = run; run += v; }
    }
    if (t == 0) rowptr[n] = E;
}

// K4d: write exclusive prefix per element
__global__ __launch_bounds__(256) void k_scanC(const int* __restrict__ deg,
                                               const int* __restrict__ bsum,
                                               int* __restrict__ rowptr, int n) {
    __shared__ int ss[256];
    int t = threadIdx.x;
    int base = blockIdx.x * 1024 + t * 4;
    int d[4]; int tsum = 0;
    #pragma unroll
    for (int i = 0; i < 4; ++i) { d[i] = (base + i < n) ? deg[base + i] : 0; tsum += d[i]; }
    ss[t] = tsum;
    __syncthreads();
    for (int off = 1; off < 256; off <<= 1) {
        int v = (t >= off) ? ss[t - off] : 0;
        __syncthreads();
        ss[t] += v;
        __syncthreads();
    }
    int excl = ss[t] - tsum + bsum[blockIdx.x];
    #pragma unroll
    for (int i = 0; i < 4; ++i) {
        if (base + i < n) rowptr[base + i] = excl;
        excl += d[i];
    }
}

// K5: compute ex = exp(leaky(e)) (max-free softmax numerator), pack (src, ex)
__global__ void k_scatter(const int* __restrict__ src, const int* __restrict__ dst,
                          const float* __restrict__ ssrc, const float* __restrict__ sdst,
                          const int* __restrict__ rowptr, int* __restrict__ cursor,
                          int2* __restrict__ csr_pair, int E) {
    int i = blockIdx.x * blockDim.x + threadIdx.x;
    if (i >= E) return;
    int s = src[i], d = dst[i];
    float e = ssrc[s] + sdst[d];
    e = e > 0.f ? e : NEG_SLOPE * e;
    float ex = __expf(e);
    int pos = rowptr[d] + atomicAdd(&cursor[d], 1);
    csr_pair[pos] = make_int2(s, __float_as_int(ex));
}

// K6: gather+accumulate. 4 rows per wave (16 lanes/row, float4 x2 per lane),
// batch-4 edges. Writes Gb[row,:] = bf16(relu(acc/denom + b_al)).
__global__ __launch_bounds__(256) void k_gat(
    const int* __restrict__ rowptr, const int2* __restrict__ csr_pair,
    const float* __restrict__ H, const float* __restrict__ b_al,
    unsigned short* __restrict__ Gb, int n) {
    int t = threadIdx.x;
    int wave = t >> 6, lane = t & 63;
    int grp = lane >> 4, gl = lane & 15;
    int row = blockIdx.x * 16 + wave * 4 + grp;
    if (row >= n) return;
    int beg = rowptr[row], end = rowptr[row + 1];
    const float4* H4 = (const float4*)H;
    float4 aA = make_float4(0.f, 0.f, 0.f, 0.f);
    float4 aB = make_float4(0.f, 0.f, 0.f, 0.f);
    float denom = 0.f;
    int j = beg;
    for (; j + 4 <= end; j += 4) {
        int2 p0 = csr_pair[j], p1 = csr_pair[j + 1];
        int2 p2 = csr_pair[j + 2], p3 = csr_pair[j + 3];
        float x0 = __int_as_float(p0.y), x1 = __int_as_float(p1.y);
        float x2 = __int_as_float(p2.y), x3 = __int_as_float(p3.y);
        const float4* b0 = H4 + (size_t)p0.x * 32;
        const float4* b1 = H4 + (size_t)p1.x * 32;
        const float4* b2 = H4 + (size_t)p2.x * 32;
        const float4* b3 = H4 + (size_t)p3.x * 32;
        float4 h0a = b0[gl], h0b = b0[16 + gl];
        float4 h1a = b1[gl], h1b = b1[16 + gl];
        float4 h2a = b2[gl], h2b = b2[16 + gl];
        float4 h3a = b3[gl], h3b = b3[16 + gl];
        denom += (x0 + x1) + (x2 + x3);
        aA.x += x0 * h0a.x + x1 * h1a.x + x2 * h2a.x + x3 * h3a.x;
        aA.y += x0 * h0a.y + x1 * h1a.y + x2 * h2a.y + x3 * h3a.y;
        aA.z += x0 * h0a.z + x1 * h1a.z + x2 * h2a.z + x3 * h3a.z;
        aA.w += x0 * h0a.w + x1 * h1a.w + x2 * h2a.w + x3 * h3a.w;
        aB.x += x0 * h0b.x + x1 * h1b.x + x2 * h2b.x + x3 * h3b.x;
        aB.y += x0 * h0b.y + x1 * h1b.y + x2 * h2b.y + x3 * h3b.y;
        aB.z += x0 * h0b.z + x1 * h1b.z + x2 * h2b.z + x3 * h3b.z;
        aB.w += x0 * h0b.w + x1 * h1b.w + x2 * h2b.w + x3 * h3b.w;
    }
    for (; j + 2 <= end; j += 2) {
        int2 p0 = csr_pair[j], p1 = csr_pair[j + 1];
        float x0 = __int_as_float(p0.y), x1 = __int_as_float(p1.y);
        const float4* b0 = H4 + (size_t)p0.x * 32;
        const float4* b1 = H4 + (size_t)p1.x * 32;
        float4 h0a = b0[gl], h0b = b0[16 + gl];
        float4 h1a = b1[gl], h1b = b1[16 + gl];
        denom += x0 + x1;
        aA.x += x0 * h0a.x + x1 * h1a.x; aA.y += x0 * h0a.y + x1 * h1a.y;
        aA.z += x0 * h0a.z + x1 * h1a.z; aA.w += x0 * h0a.w + x1 * h1a.w;
        aB.x += x0 * h0b.x + x1 * h1b.x; aB.y += x0 * h0b.y + x1 * h1b.y;
        aB.z += x0 * h0b.z + x1 * h1b.z; aB.w += x0 * h0b.w + x1 * h1b.w;
    }
    if (j < end) {
        int2 p0 = csr_pair[j];
        float x0 = __int_as_float(p0.y);
        const float4* b0 = H4 + (size_t)p0.x * 32;
        float4 h0a = b0[gl], h0b = b0[16 + gl];
        denom += x0;
        aA.x += x0 * h0a.x; aA.y += x0 * h0a.y; aA.z += x0 * h0a.z; aA.w += x0 * h0a.w;
        aB.x += x0 * h0b.x; aB.y += x0 * h0b.y; aB.z += x0 * h0b.z; aB.w += x0 * h0b.w;
    }
    float inv = denom > 0.f ? 1.f / denom : 0.f;
    const float4* B4 = (const float4*)b_al;
    float4 bA = B4[gl], bB = B4[16 + gl];
    ushort4 ga, gb;
    ga.x = f2bf(fmaxf(aA.x * inv + bA.x, 0.f)); ga.y = f2bf(fmaxf(aA.y * inv + bA.y, 0.f));
    ga.z = f2bf(fmaxf(aA.z * inv + bA.z, 0.f)); ga.w = f2bf(fmaxf(aA.w * inv + bA.w, 0.f));
    gb.x = f2bf(fmaxf(aB.x * inv + bB.x, 0.f)); gb.y = f2bf(fmaxf(aB.y * inv + bB.y, 0.f));
    gb.z = f2bf(fmaxf(aB.z * inv + bB.z, 0.f)); gb.w = f2bf(fmaxf(aB.w * inv + bB.w, 0.f));
    unsigned short* Gr = Gb + (size_t)row * 128;
    *(ushort4*)(Gr + gl * 4) = ga;
    *(ushort4*)(Gr + 64 + gl * 4) = gb;
}

// K6b: Wb[col][k] = bf16(W_lin[k][col])  (transpose + convert, 8192 elems)
__global__ void k_wconv(const float* __restrict__ Wlin, unsigned short* __restrict__ Wb) {
    int idx = blockIdx.x * 256 + threadIdx.x;   // idx = col*128 + k
    int col = idx >> 7, k = idx & 127;
    Wb[idx] = f2bf(Wlin[k * 64 + col]);
}

// K7: out = Gb @ Wb^T + b_lin via MFMA bf16.
// Block = 4 waves; wave -> 16 rows x 64 cols, K=128 (4 k-steps x 4 col-tiles).
// Fragment layouts (gfx950 16x16x32): A: m=lane&15, k=8*(lane>>4)+j;
// B: n=lane&15, same k; D: col=lane&15, row=(lane>>4)*4+reg.
__global__ __launch_bounds__(256) void k_out_mfma(
    const unsigned short* __restrict__ Gb, const unsigned short* __restrict__ Wb,
    const float* __restrict__ b_lin, float* __restrict__ out, int n) {
    int t = threadIdx.x;
    int wave = t >> 6, lane = t & 63;
    int m = lane & 15, kq = lane >> 4;
    int row0 = blockIdx.x * 64 + wave * 16;
    int ra = row0 + m;
    if (ra >= n) ra = n - 1;                        // clamp (stores are guarded)
    const bf16x8* A = (const bf16x8*)(Gb + (size_t)ra * 128);
    f32x4 acc0 = {0.f, 0.f, 0.f, 0.f};
    f32x4 acc1 = {0.f, 0.f, 0.f, 0.f};
    f32x4 acc2 = {0.f, 0.f, 0.f, 0.f};
    f32x4 acc3 = {0.f, 0.f, 0.f, 0.f};
    const bf16x8* B0 = (const bf16x8*)(Wb + (size_t)(0 * 16 + m) * 128);
    const bf16x8* B1 = (const bf16x8*)(Wb + (size_t)(1 * 16 + m) * 128);
    const bf16x8* B2 = (const bf16x8*)(Wb + (size_t)(2 * 16 + m) * 128);
    const bf16x8* B3 = (const bf16x8*)(Wb + (size_t)(3 * 16 + m) * 128);
    #pragma unroll
    for (int s = 0; s < 4; ++s) {
        int ci = s * 4 + kq;                        // K-chunk index (8 bf16 each)
        bf16x8 a = A[ci];
        acc0 = __builtin_amdgcn_mfma_f32_16x16x32_bf16(a, B0[ci], acc0, 0, 0, 0);
        acc1 = __builtin_amdgcn_mfma_f32_16x16x32_bf16(a, B1[ci], acc1, 0, 0, 0);
        acc2 = __builtin_amdgcn_mfma_f32_16x16x32_bf16(a, B2[ci], acc2, 0, 0, 0);
        acc3 = __builtin_amdgcn_mfma_f32_16x16x32_bf16(a, B3[ci], acc3, 0, 0, 0);
    }
    float bl0 = b_lin[0 * 16 + m], bl1 = b_lin[1 * 16 + m];
    float bl2 = b_lin[2 * 16 + m], bl3 = b_lin[3 * 16 + m];
    #pragma unroll
    for (int j = 0; j < 4; ++j) {
        int row = row0 + kq * 4 + j;
        if (row < n) {
            float* orow = out + (size_t)row * 64;
            orow[0 * 16 + m] = acc0[j] + bl0;
            orow[1 * 16 + m] = acc1[j] + bl1;
            orow[2 * 16 + m] = acc2[j] + bl2;
            orow[3 * 16 + m] = acc3[j] + bl3;
        }
    }
}

extern "C" void kernel_launch(void* const* d_in, const int* in_sizes, int n_in,
                              void* d_out, int out_size, void* d_ws, size_t ws_size,
                              hipStream_t stream) {
    const float* x_label  = (const float*)d_in[0];
    const float* x_attr   = (const float*)d_in[1];
    const float* W_src_al = (const float*)d_in[7];
    const float* W_dst_al = (const float*)d_in[8];
    const float* a_src_al = (const float*)d_in[9];
    const float* a_dst_al = (const float*)d_in[10];
    const float* b_al     = (const float*)d_in[11];
    const float* W_lin    = (const float*)d_in[12];
    const float* b_lin    = (const float*)d_in[13];
    const int* edge_src   = (const int*)d_in[16];
    const int* edge_dst   = (const int*)d_in[17];

    const int D = 128;
    const int N_L = in_sizes[0] / D;
    const int N_A = in_sizes[1] / D;
    const int E   = in_sizes[16];
    const int nb  = (N_L + 1023) / 1024;

    // workspace layout (all arrays 16B-aligned)
    float* ws = (float*)d_ws;
    float* h_src = ws;                                  // N_A*128 f
    float* s_src = h_src + (size_t)N_A * 128;           // N_A f
    float* s_dst = s_src + N_A;                         // N_L f
    float* wdst  = s_dst + N_L;                         // 128 f
    int*   deg    = (int*)(wdst + 128);                 // N_L i
    int*   cursor = deg + N_L;                          // N_L i
    int*   rowptr = cursor + N_L;                       // N_L+4 i (padded)
    int*   bsum   = rowptr + N_L + 4;                   // 128 i
    int2*  csr_pair = (int2*)(bsum + 128);              // E int2
    unsigned short* Gb = (unsigned short*)(csr_pair + E);   // (N_L+64)*128 bf16
    unsigned short* Wb = Gb + (size_t)(N_L + 64) * 128;     // 64*128 bf16
    float* out = (float*)d_out;

    hipMemsetAsync(deg, 0, (size_t)2 * N_L * sizeof(int), stream);  // deg + cursor

    // scalar projections
    k_wdst<<<1, 128, 0, stream>>>(W_dst_al, a_dst_al, wdst);
    k_rowdot<<<(N_L + 7) / 8, 256, 0, stream>>>(x_label, wdst, s_dst, N_L);
    // h_src GEMM + its scalar projection
    k_hsrc<<<(N_A + 31) / 32, 256, 0, stream>>>(x_attr, W_src_al, h_src, N_A);
    k_rowdot<<<(N_A + 7) / 8, 256, 0, stream>>>(h_src, a_src_al, s_src, N_A);
    // W_lin -> bf16 transposed (runs early, independent)
    k_wconv<<<32, 256, 0, stream>>>(W_lin, Wb);
    // CSR build (ex precomputed at scatter)
    k_deg<<<(E + 255) / 256, 256, 0, stream>>>(edge_dst, deg, E);
    k_scanA<<<nb, 256, 0, stream>>>(deg, bsum, N_L);
    k_scanB<<<1, 128, 0, stream>>>(bsum, nb, rowptr, N_L, E);
    k_scanC<<<nb, 256, 0, stream>>>(deg, bsum, rowptr, N_L);
    k_scatter<<<(E + 255) / 256, 256, 0, stream>>>(edge_src, edge_dst, s_src, s_dst,
                                                   rowptr, cursor, csr_pair, E);
    // gather + normalize + bias + relu -> Gb (bf16)
    k_gat<<<(N_L + 15) / 16, 256, 0, stream>>>(rowptr, csr_pair, h_src, b_al, Gb, N_L);
    // final GEMM via MFMA
    k_out_mfma<<<(N_L + 63) / 64, 256, 0, stream>>>(Gb, Wb, b_lin, out, N_L);
}

// Round 7
// 258.506 us; speedup vs baseline: 1.3681x; 1.0394x over previous
//
#include <hip/hip_runtime.h>
#include <math.h>

#define NEG_SLOPE 0.2f

typedef __attribute__((ext_vector_type(8))) short bf16x8;
typedef __attribute__((ext_vector_type(4))) float f32x4;

// float -> bf16 bits, round-to-nearest-even
__device__ __forceinline__ unsigned short f2bf(float f) {
    unsigned u = __float_as_uint(f);
    unsigned r = (u + 0x7FFFu + ((u >> 16) & 1u)) >> 16;
    return (unsigned short)r;
}

// unpack uint (2 bf16) -> 2 floats, accumulate
__device__ __forceinline__ void acc8(float* a, uint4 u, float x) {
    a[0] += x * __uint_as_float(u.x << 16);
    a[1] += x * __uint_as_float(u.x & 0xFFFF0000u);
    a[2] += x * __uint_as_float(u.y << 16);
    a[3] += x * __uint_as_float(u.y & 0xFFFF0000u);
    a[4] += x * __uint_as_float(u.z << 16);
    a[5] += x * __uint_as_float(u.z & 0xFFFF0000u);
    a[6] += x * __uint_as_float(u.w << 16);
    a[7] += x * __uint_as_float(u.w & 0xFFFF0000u);
}

// K1: wdst[d] = sum_h W_dst[d,h]*a_dst[h];  wsrc[d] = sum_h W_src[d,h]*a_src[h]
// (s_src = (x@W)@a = x@(W@a) -- exact same fp32 dot structure)
__global__ void k_wvec(const float* __restrict__ Wd, const float* __restrict__ ad,
                       const float* __restrict__ Ws, const float* __restrict__ as_,
                       float* __restrict__ wdst, float* __restrict__ wsrc) {
    int t = threadIdx.x;
    const float* W = (t < 128) ? Wd : Ws;
    const float* a = (t < 128) ? ad : as_;
    int d = t & 127;
    float s = 0.f;
    #pragma unroll 8
    for (int h = 0; h < 128; ++h) s += W[d * 128 + h] * a[h];
    if (t < 128) wdst[d] = s; else wsrc[d] = s;
}

// K2: out[row] = dot(X[row,0:128], v). 2 rows per wave, float4/lane, coalesced.
__global__ void k_rowdot(const float* __restrict__ X, const float* __restrict__ v,
                         float* __restrict__ out, int n) {
    int gw = (int)((blockIdx.x * blockDim.x + threadIdx.x) >> 6);
    int lane = threadIdx.x & 63;
    int half = lane >> 5, li = lane & 31;
    int row = gw * 2 + half;
    if (row >= n) return;
    const float4* X4 = (const float4*)X;
    const float4* V4 = (const float4*)v;
    float4 x = X4[(size_t)row * 32 + li];
    float4 b = V4[li];
    float p = x.x * b.x + x.y * b.y + x.z * b.z + x.w * b.w;
    #pragma unroll
    for (int off = 16; off; off >>= 1) p += __shfl_xor(p, off);
    if (li == 0) out[row] = p;
}

// K3: Hb = bf16(X @ W)  (X: nrows x 128, W: 128 x 128). 32 rows/block, 4x4 tile.
__global__ __launch_bounds__(256) void k_hsrc(const float* __restrict__ X,
                                              const float* __restrict__ W,
                                              unsigned short* __restrict__ Hb, int nrows) {
    __shared__ float Xs[32][128];
    int t = threadIdx.x;
    int row0 = blockIdx.x * 32;
    #pragma unroll
    for (int i = 0; i < 16; ++i) {
        int idx = t + i * 256;
        int r = idx >> 7;
        Xs[r][idx & 127] = (row0 + r < nrows) ? X[(size_t)row0 * 128 + idx] : 0.f;
    }
    __syncthreads();
    int cg = t & 31, rg = t >> 5;
    float acc[4][4];
    #pragma unroll
    for (int i = 0; i < 4; ++i)
        #pragma unroll
        for (int j = 0; j < 4; ++j) acc[i][j] = 0.f;
    const float4* W4 = (const float4*)W;
    #pragma unroll 4
    for (int d = 0; d < 128; ++d) {
        float4 wv = W4[d * 32 + cg];
        float x0 = Xs[rg * 4 + 0][d], x1 = Xs[rg * 4 + 1][d];
        float x2 = Xs[rg * 4 + 2][d], x3 = Xs[rg * 4 + 3][d];
        acc[0][0] += x0 * wv.x; acc[0][1] += x0 * wv.y; acc[0][2] += x0 * wv.z; acc[0][3] += x0 * wv.w;
        acc[1][0] += x1 * wv.x; acc[1][1] += x1 * wv.y; acc[1][2] += x1 * wv.z; acc[1][3] += x1 * wv.w;
        acc[2][0] += x2 * wv.x; acc[2][1] += x2 * wv.y; acc[2][2] += x2 * wv.z; acc[2][3] += x2 * wv.w;
        acc[3][0] += x3 * wv.x; acc[3][1] += x3 * wv.y; acc[3][2] += x3 * wv.z; acc[3][3] += x3 * wv.w;
    }
    #pragma unroll
    for (int i = 0; i < 4; ++i) {
        int gr = row0 + rg * 4 + i;
        if (gr < nrows) {
            ushort4 o;
            o.x = f2bf(acc[i][0]); o.y = f2bf(acc[i][1]);
            o.z = f2bf(acc[i][2]); o.w = f2bf(acc[i][3]);
            *(ushort4*)&Hb[(size_t)gr * 128 + cg * 4] = o;
        }
    }
}

// K4a: degree histogram of dst
__global__ void k_deg(const int* __restrict__ dst, int* __restrict__ deg, int E) {
    int i = blockIdx.x * blockDim.x + threadIdx.x;
    if (i < E) atomicAdd(&deg[dst[i]], 1);
}

// K4b: per-1024-chunk block sums
__global__ __launch_bounds__(256) void k_scanA(const int* __restrict__ deg,
                                               int* __restrict__ bsum, int n) {
    __shared__ int sd[256];
    int t = threadIdx.x;
    int base = blockIdx.x * 1024 + t * 4;
    int s = 0;
    #pragma unroll
    for (int i = 0; i < 4; ++i) if (base + i < n) s += deg[base + i];
    sd[t] = s;
    __syncthreads();
    for (int off = 128; off; off >>= 1) {
        if (t < off) sd[t] += sd[t + off];
        __syncthreads();
    }
    if (t == 0) bsum[blockIdx.x] = sd[0];
}

// K4c: parallel exclusive scan of block sums
__global__ __launch_bounds__(128) void k_scanB(int* __restrict__ bsum, int nb,
                                               int* __restrict__ rowptr, int n, int E) {
    __shared__ int ss[128];
    int t = threadIdx.x;
    if (nb <= 128) {
        int v = (t < nb) ? bsum[t] : 0;
        ss[t] = v;
        __syncthreads();
        for (int off = 1; off < 128; off <<= 1) {
            int u = (t >= off) ? ss[t - off] : 0;
            __syncthreads();
            ss[t] += u;
            __syncthreads();
        }
        if (t < nb) bsum[t] = ss[t] - v;
    } else if (t == 0) {
        int run = 0;
        for (int i = 0; i < nb; ++i) { int v = bsum[i]; bsum[i] = run; run += v; }
    }
    if (t == 0) rowptr[n] = E;
}

// K4d: write exclusive prefix per element
__global__ __launch_bounds__(256) void k_scanC(const int* __restrict__ deg,
                                               const int* __restrict__ bsum,
                                               int* __restrict__ rowptr, int n) {
    __shared__ int ss[256];
    int t = threadIdx.x;
    int base = blockIdx.x * 1024 + t * 4;
    int d[4]; int tsum = 0;
    #pragma unroll
    for (int i = 0; i < 4; ++i) { d[i] = (base + i < n) ? deg[base + i] : 0; tsum += d[i]; }
    ss[t] = tsum;
    __syncthreads();
    for (int off = 1; off < 256; off <<= 1) {
        int v = (t >= off) ? ss[t - off] : 0;
        __syncthreads();
        ss[t] += v;
        __syncthreads();
    }
    int excl = ss[t] - tsum + bsum[blockIdx.x];
    #pragma unroll
    for (int i = 0; i < 4; ++i) {
        if (base + i < n) rowptr[base + i] = excl;
        excl += d[i];
    }
}

// K5: compute ex = exp(leaky(e)) (max-free softmax numerator), pack (src, ex)
__global__ void k_scatter(const int* __restrict__ src, const int* __restrict__ dst,
                          const float* __restrict__ ssrc, const float* __restrict__ sdst,
                          const int* __restrict__ rowptr, int* __restrict__ cursor,
                          int2* __restrict__ csr_pair, int E) {
    int i = blockIdx.x * blockDim.x + threadIdx.x;
    if (i >= E) return;
    int s = src[i], d = dst[i];
    float e = ssrc[s] + sdst[d];
    e = e > 0.f ? e : NEG_SLOPE * e;
    float ex = __expf(e);
    int pos = rowptr[d] + atomicAdd(&cursor[d], 1);
    csr_pair[pos] = make_int2(s, __float_as_int(ex));
}

// K6: gather+accumulate over bf16 H. 4 rows per wave, 16 lanes/row, one 16B
// (8 bf16) load per lane per edge, batch-4. Gb[row,:] = bf16(relu(acc/denom+b)).
__global__ __launch_bounds__(256) void k_gat(
    const int* __restrict__ rowptr, const int2* __restrict__ csr_pair,
    const unsigned short* __restrict__ Hb, const float* __restrict__ b_al,
    unsigned short* __restrict__ Gb, int n) {
    int t = threadIdx.x;
    int wave = t >> 6, lane = t & 63;
    int grp = lane >> 4, gl = lane & 15;
    int row = blockIdx.x * 16 + wave * 4 + grp;
    if (row >= n) return;
    int beg = rowptr[row], end = rowptr[row + 1];
    const uint4* H16 = (const uint4*)Hb;           // row stride = 16 chunks of 16B
    float a[8];
    #pragma unroll
    for (int k = 0; k < 8; ++k) a[k] = 0.f;
    float denom = 0.f;
    int j = beg;
    for (; j + 4 <= end; j += 4) {
        int2 p0 = csr_pair[j], p1 = csr_pair[j + 1];
        int2 p2 = csr_pair[j + 2], p3 = csr_pair[j + 3];
        float x0 = __int_as_float(p0.y), x1 = __int_as_float(p1.y);
        float x2 = __int_as_float(p2.y), x3 = __int_as_float(p3.y);
        uint4 u0 = H16[(size_t)p0.x * 16 + gl];
        uint4 u1 = H16[(size_t)p1.x * 16 + gl];
        uint4 u2 = H16[(size_t)p2.x * 16 + gl];
        uint4 u3 = H16[(size_t)p3.x * 16 + gl];
        denom += (x0 + x1) + (x2 + x3);
        acc8(a, u0, x0); acc8(a, u1, x1); acc8(a, u2, x2); acc8(a, u3, x3);
    }
    for (; j + 2 <= end; j += 2) {
        int2 p0 = csr_pair[j], p1 = csr_pair[j + 1];
        float x0 = __int_as_float(p0.y), x1 = __int_as_float(p1.y);
        uint4 u0 = H16[(size_t)p0.x * 16 + gl];
        uint4 u1 = H16[(size_t)p1.x * 16 + gl];
        denom += x0 + x1;
        acc8(a, u0, x0); acc8(a, u1, x1);
    }
    if (j < end) {
        int2 p0 = csr_pair[j];
        float x0 = __int_as_float(p0.y);
        uint4 u0 = H16[(size_t)p0.x * 16 + gl];
        denom += x0;
        acc8(a, u0, x0);
    }
    float inv = denom > 0.f ? 1.f / denom : 0.f;
    const float4* B4 = (const float4*)b_al;
    float4 bA = B4[gl * 2], bB = B4[gl * 2 + 1];
    ushort4 ga, gb;
    ga.x = f2bf(fmaxf(a[0] * inv + bA.x, 0.f)); ga.y = f2bf(fmaxf(a[1] * inv + bA.y, 0.f));
    ga.z = f2bf(fmaxf(a[2] * inv + bA.z, 0.f)); ga.w = f2bf(fmaxf(a[3] * inv + bA.w, 0.f));
    gb.x = f2bf(fmaxf(a[4] * inv + bB.x, 0.f)); gb.y = f2bf(fmaxf(a[5] * inv + bB.y, 0.f));
    gb.z = f2bf(fmaxf(a[6] * inv + bB.z, 0.f)); gb.w = f2bf(fmaxf(a[7] * inv + bB.w, 0.f));
    unsigned short* Gr = Gb + (size_t)row * 128 + gl * 8;
    *(ushort4*)Gr = ga;
    *(ushort4*)(Gr + 4) = gb;
}

// K6b: Wb[col][k] = bf16(W_lin[k][col])  (transpose + convert, 8192 elems)
__global__ void k_wconv(const float* __restrict__ Wlin, unsigned short* __restrict__ Wb) {
    int idx = blockIdx.x * 256 + threadIdx.x;   // idx = col*128 + k
    int col = idx >> 7, k = idx & 127;
    Wb[idx] = f2bf(Wlin[k * 64 + col]);
}

// K7: out = Gb @ Wb^T + b_lin via MFMA bf16.
// Wave -> 16 rows x 64 cols, K=128. A: m=lane&15, k=8*(lane>>4)+j; B: n=lane&15;
// D: col=lane&15, row=(lane>>4)*4+reg  (m89-verified layouts).
__global__ __launch_bounds__(256) void k_out_mfma(
    const unsigned short* __restrict__ Gb, const unsigned short* __restrict__ Wb,
    const float* __restrict__ b_lin, float* __restrict__ out, int n) {
    int t = threadIdx.x;
    int wave = t >> 6, lane = t & 63;
    int m = lane & 15, kq = lane >> 4;
    int row0 = blockIdx.x * 64 + wave * 16;
    int ra = row0 + m;
    if (ra >= n) ra = n - 1;                        // clamp (stores are guarded)
    const bf16x8* A = (const bf16x8*)(Gb + (size_t)ra * 128);
    f32x4 acc0 = {0.f, 0.f, 0.f, 0.f};
    f32x4 acc1 = {0.f, 0.f, 0.f, 0.f};
    f32x4 acc2 = {0.f, 0.f, 0.f, 0.f};
    f32x4 acc3 = {0.f, 0.f, 0.f, 0.f};
    const bf16x8* B0 = (const bf16x8*)(Wb + (size_t)(0 * 16 + m) * 128);
    const bf16x8* B1 = (const bf16x8*)(Wb + (size_t)(1 * 16 + m) * 128);
    const bf16x8* B2 = (const bf16x8*)(Wb + (size_t)(2 * 16 + m) * 128);
    const bf16x8* B3 = (const bf16x8*)(Wb + (size_t)(3 * 16 + m) * 128);
    #pragma unroll
    for (int s = 0; s < 4; ++s) {
        int ci = s * 4 + kq;                        // K-chunk index (8 bf16 each)
        bf16x8 a = A[ci];
        acc0 = __builtin_amdgcn_mfma_f32_16x16x32_bf16(a, B0[ci], acc0, 0, 0, 0);
        acc1 = __builtin_amdgcn_mfma_f32_16x16x32_bf16(a, B1[ci], acc1, 0, 0, 0);
        acc2 = __builtin_amdgcn_mfma_f32_16x16x32_bf16(a, B2[ci], acc2, 0, 0, 0);
        acc3 = __builtin_amdgcn_mfma_f32_16x16x32_bf16(a, B3[ci], acc3, 0, 0, 0);
    }
    float bl0 = b_lin[0 * 16 + m], bl1 = b_lin[1 * 16 + m];
    float bl2 = b_lin[2 * 16 + m], bl3 = b_lin[3 * 16 + m];
    #pragma unroll
    for (int j = 0; j < 4; ++j) {
        int row = row0 + kq * 4 + j;
        if (row < n) {
            float* orow = out + (size_t)row * 64;
            orow[0 * 16 + m] = acc0[j] + bl0;
            orow[1 * 16 + m] = acc1[j] + bl1;
            orow[2 * 16 + m] = acc2[j] + bl2;
            orow[3 * 16 + m] = acc3[j] + bl3;
        }
    }
}

extern "C" void kernel_launch(void* const* d_in, const int* in_sizes, int n_in,
                              void* d_out, int out_size, void* d_ws, size_t ws_size,
                              hipStream_t stream) {
    const float* x_label  = (const float*)d_in[0];
    const float* x_attr   = (const float*)d_in[1];
    const float* W_src_al = (const float*)d_in[7];
    const float* W_dst_al = (const float*)d_in[8];
    const float* a_src_al = (const float*)d_in[9];
    const float* a_dst_al = (const float*)d_in[10];
    const float* b_al     = (const float*)d_in[11];
    const float* W_lin    = (const float*)d_in[12];
    const float* b_lin    = (const float*)d_in[13];
    const int* edge_src   = (const int*)d_in[16];
    const int* edge_dst   = (const int*)d_in[17];

    const int D = 128;
    const int N_L = in_sizes[0] / D;
    const int N_A = in_sizes[1] / D;
    const int E   = in_sizes[16];
    const int nb  = (N_L + 1023) / 1024;

    // workspace layout (all arrays 16B-aligned)
    float* ws = (float*)d_ws;
    float* s_src = ws;                                  // N_A f
    float* s_dst = s_src + N_A;                         // N_L f
    float* wdst  = s_dst + N_L;                         // 128 f
    float* wsrc  = wdst + 128;                          // 128 f
    int*   deg    = (int*)(wsrc + 128);                 // N_L i
    int*   cursor = deg + N_L;                          // N_L i
    int*   rowptr = cursor + N_L;                       // N_L+4 i (padded)
    int*   bsum   = rowptr + N_L + 4;                   // 128 i
    int2*  csr_pair = (int2*)(bsum + 128);              // E int2
    unsigned short* Hb = (unsigned short*)(csr_pair + E);   // N_A*128 bf16
    unsigned short* Gb = Hb + (size_t)N_A * 128;            // (N_L+64)*128 bf16
    unsigned short* Wb = Gb + (size_t)(N_L + 64) * 128;     // 64*128 bf16
    float* out = (float*)d_out;

    hipMemsetAsync(deg, 0, (size_t)2 * N_L * sizeof(int), stream);  // deg + cursor

    // weight->vector projections (both GATs' scalar vectors)
    k_wvec<<<1, 256, 0, stream>>>(W_dst_al, a_dst_al, W_src_al, a_src_al, wdst, wsrc);
    // s_dst from x_label, s_src directly from x_attr (no h_src dependency)
    k_rowdot<<<(N_L + 7) / 8, 256, 0, stream>>>(x_label, wdst, s_dst, N_L);
    k_rowdot<<<(N_A + 7) / 8, 256, 0, stream>>>(x_attr, wsrc, s_src, N_A);
    // W_lin -> bf16 transposed
    k_wconv<<<32, 256, 0, stream>>>(W_lin, Wb);
    // h_src GEMM -> bf16 (overlaps CSR build)
    k_hsrc<<<(N_A + 31) / 32, 256, 0, stream>>>(x_attr, W_src_al, Hb, N_A);
    // CSR build (ex precomputed at scatter)
    k_deg<<<(E + 255) / 256, 256, 0, stream>>>(edge_dst, deg, E);
    k_scanA<<<nb, 256, 0, stream>>>(deg, bsum, N_L);
    k_scanB<<<1, 128, 0, stream>>>(bsum, nb, rowptr, N_L, E);
    k_scanC<<<nb, 256, 0, stream>>>(deg, bsum, rowptr, N_L);
    k_scatter<<<(E + 255) / 256, 256, 0, stream>>>(edge_src, edge_dst, s_src, s_dst,
                                                   rowptr, cursor, csr_pair, E);
    // gather + normalize + bias + relu -> Gb (bf16)
    k_gat<<<(N_L + 15) / 16, 256, 0, stream>>>(rowptr, csr_pair, Hb, b_al, Gb, N_L);
    // final GEMM via MFMA
    k_out_mfma<<<(N_L + 63) / 64, 256, 0, stream>>>(Gb, Wb, b_lin, out, N_L);
}

// Round 9
// 257.543 us; speedup vs baseline: 1.3732x; 1.0037x over previous
//
#include <hip/hip_runtime.h>
#include <math.h>

#define NEG_SLOPE 0.2f

typedef __attribute__((ext_vector_type(8))) short bf16x8;
typedef __attribute__((ext_vector_type(4))) float f32x4;

// float -> bf16 bits, round-to-nearest-even
__device__ __forceinline__ unsigned short f2bf(float f) {
    unsigned u = __float_as_uint(f);
    unsigned r = (u + 0x7FFFu + ((u >> 16) & 1u)) >> 16;
    return (unsigned short)r;
}

// unpack uint4 (8 bf16) -> accumulate a[0..7] += x * h[k]
__device__ __forceinline__ void acc8(float* a, uint4 u, float x) {
    a[0] += x * __uint_as_float(u.x << 16);
    a[1] += x * __uint_as_float(u.x & 0xFFFF0000u);
    a[2] += x * __uint_as_float(u.y << 16);
    a[3] += x * __uint_as_float(u.y & 0xFFFF0000u);
    a[4] += x * __uint_as_float(u.z << 16);
    a[5] += x * __uint_as_float(u.z & 0xFFFF0000u);
    a[6] += x * __uint_as_float(u.w << 16);
    a[7] += x * __uint_as_float(u.w & 0xFFFF0000u);
}

__device__ __forceinline__ unsigned pack2(unsigned short lo, unsigned short hi) {
    return (unsigned)lo | ((unsigned)hi << 16);
}

// ---------------- K_PRE: {deg histogram | wvec | wconv} ----------------
__global__ __launch_bounds__(256) void k_pre(
    const int* __restrict__ dst, int* __restrict__ deg, int E, int nbDeg,
    const float* __restrict__ Wd, const float* __restrict__ ad,
    const float* __restrict__ Ws, const float* __restrict__ as_,
    float* __restrict__ wdst, float* __restrict__ wsrc,
    const float* __restrict__ Wlin, unsigned short* __restrict__ Wb) {
    int b = blockIdx.x, t = threadIdx.x;
    if (b < nbDeg) {
        int i = b * 256 + t;
        if (i < E) atomicAdd(&deg[dst[i]], 1);
    } else if (b == nbDeg) {
        // wdst[d] = sum_h W_dst[d,h]*a_dst[h]; wsrc[d] = sum_h W_src[d,h]*a_src[h]
        const float* W = (t < 128) ? Wd : Ws;
        const float* a = (t < 128) ? ad : as_;
        int d = t & 127;
        float s = 0.f;
        #pragma unroll 8
        for (int h = 0; h < 128; ++h) s += W[d * 128 + h] * a[h];
        if (t < 128) wdst[d] = s; else wsrc[d] = s;
    } else {
        // Wb[col][k] = bf16(W_lin[k][col])
        int idx = (b - nbDeg - 1) * 256 + t;
        int col = idx >> 7, k = idx & 127;
        Wb[idx] = f2bf(Wlin[k * 64 + col]);
    }
}

// ---------------- role helpers for K_MID ----------------
__device__ __forceinline__ void rowdot_role(const float* __restrict__ X,
                                            const float* __restrict__ v,
                                            float* __restrict__ out, int n,
                                            int vb, int t) {
    int gw = vb * 4 + (t >> 6);
    int lane = t & 63;
    int half = lane >> 5, li = lane & 31;
    int row = gw * 2 + half;
    if (row >= n) return;
    const float4* X4 = (const float4*)X;
    const float4* V4 = (const float4*)v;
    float4 x = X4[(size_t)row * 32 + li];
    float4 b = V4[li];
    float p = x.x * b.x + x.y * b.y + x.z * b.z + x.w * b.w;
    #pragma unroll
    for (int off = 16; off; off >>= 1) p += __shfl_xor(p, off);
    if (li == 0) out[row] = p;
}

__device__ __forceinline__ void hsrc_role(const float* __restrict__ X,
                                          const float* __restrict__ W,
                                          unsigned short* __restrict__ Hb,
                                          int nrows, int row0, int t,
                                          float* __restrict__ Xs /*32*128 lds*/) {
    #pragma unroll
    for (int i = 0; i < 16; ++i) {
        int idx = t + i * 256;
        int r = idx >> 7;
        Xs[r * 128 + (idx & 127)] = (row0 + r < nrows) ? X[(size_t)row0 * 128 + idx] : 0.f;
    }
    __syncthreads();
    int cg = t & 31, rg = t >> 5;
    float acc[4][4];
    #pragma unroll
    for (int i = 0; i < 4; ++i)
        #pragma unroll
        for (int j = 0; j < 4; ++j) acc[i][j] = 0.f;
    const float4* W4 = (const float4*)W;
    #pragma unroll 4
    for (int d = 0; d < 128; ++d) {
        float4 wv = W4[d * 32 + cg];
        float x0 = Xs[(rg * 4 + 0) * 128 + d], x1 = Xs[(rg * 4 + 1) * 128 + d];
        float x2 = Xs[(rg * 4 + 2) * 128 + d], x3 = Xs[(rg * 4 + 3) * 128 + d];
        acc[0][0] += x0 * wv.x; acc[0][1] += x0 * wv.y; acc[0][2] += x0 * wv.z; acc[0][3] += x0 * wv.w;
        acc[1][0] += x1 * wv.x; acc[1][1] += x1 * wv.y; acc[1][2] += x1 * wv.z; acc[1][3] += x1 * wv.w;
        acc[2][0] += x2 * wv.x; acc[2][1] += x2 * wv.y; acc[2][2] += x2 * wv.z; acc[2][3] += x2 * wv.w;
        acc[3][0] += x3 * wv.x; acc[3][1] += x3 * wv.y; acc[3][2] += x3 * wv.z; acc[3][3] += x3 * wv.w;
    }
    #pragma unroll
    for (int i = 0; i < 4; ++i) {
        int gr = row0 + rg * 4 + i;
        if (gr < nrows) {
            ushort4 o;
            o.x = f2bf(acc[i][0]); o.y = f2bf(acc[i][1]);
            o.z = f2bf(acc[i][2]); o.w = f2bf(acc[i][3]);
            *(ushort4*)&Hb[(size_t)gr * 128 + cg * 4] = o;
        }
    }
}

// ---------------- K_MID: {scanA | rowdot(xL) | rowdot(xA) | hsrc} ----------------
// scanA role: per-1024-chunk sums of deg -> bsum (safe, no inter-block deps)
__global__ __launch_bounds__(256) void k_mid(
    const int* __restrict__ deg, int* __restrict__ bsum, int nScan, int n,
    const float* __restrict__ xL, const float* __restrict__ wdst,
    float* __restrict__ sdst, int nRL, int NL,
    const float* __restrict__ xA, const float* __restrict__ wsrc,
    float* __restrict__ ssrc, int nRA, int NA,
    const float* __restrict__ Wsrc, unsigned short* __restrict__ Hb) {
    __shared__ float smemf[32 * 128];
    int b = blockIdx.x, t = threadIdx.x;
    if (b < nScan) {
        int* sd = (int*)smemf;
        int base = b * 1024 + t * 4;
        int s = 0;
        #pragma unroll
        for (int i = 0; i < 4; ++i) if (base + i < n) s += deg[base + i];
        sd[t] = s;
        __syncthreads();
        for (int off = 128; off; off >>= 1) {
            if (t < off) sd[t] += sd[t + off];
            __syncthreads();
        }
        if (t == 0) bsum[b] = sd[0];
    } else if (b < nScan + nRL) {
        rowdot_role(xL, wdst, sdst, NL, b - nScan, t);
    } else if (b < nScan + nRL + nRA) {
        rowdot_role(xA, wsrc, ssrc, NA, b - nScan - nRL, t);
    } else {
        hsrc_role(xA, Wsrc, Hb, NA, (b - nScan - nRL - nRA) * 32, t, smemf);
    }
}

// K_SCANB: parallel exclusive scan of block sums (nb <= 128; serial fallback)
__global__ __launch_bounds__(128) void k_scanB(int* __restrict__ bsum, int nb,
                                               int* __restrict__ rowptr, int n, int E) {
    __shared__ int ss[128];
    int t = threadIdx.x;
    if (nb <= 128) {
        int v = (t < nb) ? bsum[t] : 0;
        ss[t] = v;
        __syncthreads();
        for (int off = 1; off < 128; off <<= 1) {
            int u = (t >= off) ? ss[t - off] : 0;
            __syncthreads();
            ss[t] += u;
            __syncthreads();
        }
        if (t < nb) bsum[t] = ss[t] - v;
    } else if (t == 0) {
        int run = 0;
        for (int i = 0; i < nb; ++i) { int v = bsum[i]; bsum[i] = run; run += v; }
    }
    if (t == 0) rowptr[n] = E;
}

// K_SCANC: write exclusive prefix per element
__global__ __launch_bounds__(256) void k_scanC(const int* __restrict__ deg,
                                               const int* __restrict__ bsum,
                                               int* __restrict__ rowptr, int n) {
    __shared__ int ss[256];
    int t = threadIdx.x;
    int base = blockIdx.x * 1024 + t * 4;
    int d[4]; int tsum = 0;
    #pragma unroll
    for (int i = 0; i < 4; ++i) { d[i] = (base + i < n) ? deg[base + i] : 0; tsum += d[i]; }
    ss[t] = tsum;
    __syncthreads();
    for (int off = 1; off < 256; off <<= 1) {
        int v = (t >= off) ? ss[t - off] : 0;
        __syncthreads();
        ss[t] += v;
        __syncthreads();
    }
    int excl = ss[t] - tsum + bsum[blockIdx.x];
    #pragma unroll
    for (int i = 0; i < 4; ++i) {
        if (base + i < n) rowptr[base + i] = excl;
        excl += d[i];
    }
}

// ---------------- K_SCATTER: ex = exp(leaky(e)); place (src,ex) in CSR slot ----------------
__global__ void k_scatter(const int* __restrict__ src, const int* __restrict__ dst,
                          const float* __restrict__ ssrc, const float* __restrict__ sdst,
                          const int* __restrict__ rowptr, int* __restrict__ cursor,
                          int2* __restrict__ csr_pair, int E) {
    int i = blockIdx.x * blockDim.x + threadIdx.x;
    if (i >= E) return;
    int s = src[i], d = dst[i];
    float e = ssrc[s] + sdst[d];
    e = e > 0.f ? e : NEG_SLOPE * e;
    float ex = __expf(e);
    int pos = rowptr[d] + atomicAdd(&cursor[d], 1);
    csr_pair[pos] = make_int2(s, __float_as_int(ex));
}

// ---------------- K_GATOUT: gather -> G tile in LDS -> MFMA epilogue ----------------
// Block = 4 waves = 64 dst rows. Phase 1: each wave gathers 4 rows x 4 passes
// (16 lanes/row, one 16B bf16x8 load/edge), writes swizzled G to LDS.
// Phase 2: wave w MFMAs rows [w*16, w*16+16) x 64 cols, K=128, A from LDS.
__global__ __launch_bounds__(256) void k_gatout(
    const int* __restrict__ rowptr, const int2* __restrict__ csr_pair,
    const unsigned short* __restrict__ Hb, const float* __restrict__ b_al,
    const unsigned short* __restrict__ Wb, const float* __restrict__ b_lin,
    float* __restrict__ out, int n) {
    __shared__ unsigned short Gs[64 * 128];   // 16 KB, 16B slots XOR-swizzled
    int t = threadIdx.x;
    int wave = t >> 6, lane = t & 63;
    int grp = lane >> 4, gl = lane & 15;
    const uint4* H16 = (const uint4*)Hb;
    int row0b = blockIdx.x * 64;
    const float4* B4 = (const float4*)b_al;
    float4 bA = B4[gl * 2], bB = B4[gl * 2 + 1];

    #pragma unroll
    for (int rr = 0; rr < 4; ++rr) {
        int rl = wave * 16 + rr * 4 + grp;     // local row 0..63
        int row = row0b + rl;
        uint4 gpack = make_uint4(0u, 0u, 0u, 0u);
        if (row < n) {
            int beg = rowptr[row], end = rowptr[row + 1];
            float a[8];
            #pragma unroll
            for (int k = 0; k < 8; ++k) a[k] = 0.f;
            float denom = 0.f;
            int j = beg;
            for (; j + 4 <= end; j += 4) {
                int2 p0 = csr_pair[j], p1 = csr_pair[j + 1];
                int2 p2 = csr_pair[j + 2], p3 = csr_pair[j + 3];
                float x0 = __int_as_float(p0.y), x1 = __int_as_float(p1.y);
                float x2 = __int_as_float(p2.y), x3 = __int_as_float(p3.y);
                uint4 u0 = H16[(size_t)p0.x * 16 + gl];
                uint4 u1 = H16[(size_t)p1.x * 16 + gl];
                uint4 u2 = H16[(size_t)p2.x * 16 + gl];
                uint4 u3 = H16[(size_t)p3.x * 16 + gl];
                denom += (x0 + x1) + (x2 + x3);
                acc8(a, u0, x0); acc8(a, u1, x1); acc8(a, u2, x2); acc8(a, u3, x3);
            }
            for (; j + 2 <= end; j += 2) {
                int2 p0 = csr_pair[j], p1 = csr_pair[j + 1];
                float x0 = __int_as_float(p0.y), x1 = __int_as_float(p1.y);
                uint4 u0 = H16[(size_t)p0.x * 16 + gl];
                uint4 u1 = H16[(size_t)p1.x * 16 + gl];
                denom += x0 + x1;
                acc8(a, u0, x0); acc8(a, u1, x1);
            }
            if (j < end) {
                int2 p0 = csr_pair[j];
                float x0 = __int_as_float(p0.y);
                uint4 u0 = H16[(size_t)p0.x * 16 + gl];
                denom += x0;
                acc8(a, u0, x0);
            }
            float inv = denom > 0.f ? 1.f / denom : 0.f;
            unsigned short g0 = f2bf(fmaxf(a[0] * inv + bA.x, 0.f));
            unsigned short g1 = f2bf(fmaxf(a[1] * inv + bA.y, 0.f));
            unsigned short g2 = f2bf(fmaxf(a[2] * inv + bA.z, 0.f));
            unsigned short g3 = f2bf(fmaxf(a[3] * inv + bA.w, 0.f));
            unsigned short g4 = f2bf(fmaxf(a[4] * inv + bB.x, 0.f));
            unsigned short g5 = f2bf(fmaxf(a[5] * inv + bB.y, 0.f));
            unsigned short g6 = f2bf(fmaxf(a[6] * inv + bB.z, 0.f));
            unsigned short g7 = f2bf(fmaxf(a[7] * inv + bB.w, 0.f));
            gpack = make_uint4(pack2(g0, g1), pack2(g2, g3), pack2(g4, g5), pack2(g6, g7));
        }
        int slot = gl ^ (rl & 15);             // swizzle: conflict-free phase-2 reads
        *(uint4*)&Gs[rl * 128 + slot * 8] = gpack;
    }
    __syncthreads();

    // phase 2: MFMA. A: m=lane&15, k-chunk ci=s*4+kq; B: n=lane&15;
    // D: col=lane&15, row=(lane>>4)*4+reg (m89-verified layouts).
    int m = lane & 15, kq = lane >> 4;
    int rl = wave * 16 + m;
    f32x4 acc0 = {0.f, 0.f, 0.f, 0.f};
    f32x4 acc1 = {0.f, 0.f, 0.f, 0.f};
    f32x4 acc2 = {0.f, 0.f, 0.f, 0.f};
    f32x4 acc3 = {0.f, 0.f, 0.f, 0.f};
    const bf16x8* B0 = (const bf16x8*)(Wb + (size_t)(0 * 16 + m) * 128);
    const bf16x8* B1 = (const bf16x8*)(Wb + (size_t)(1 * 16 + m) * 128);
    const bf16x8* B2 = (const bf16x8*)(Wb + (size_t)(2 * 16 + m) * 128);
    const bf16x8* B3 = (const bf16x8*)(Wb + (size_t)(3 * 16 + m) * 128);
    #pragma unroll
    for (int s = 0; s < 4; ++s) {
        int ci = s * 4 + kq;
        int slot = ci ^ m;                     // rl&15 == m
        bf16x8 a = *(const bf16x8*)&Gs[rl * 128 + slot * 8];
        acc0 = __builtin_amdgcn_mfma_f32_16x16x32_bf16(a, B0[ci], acc0, 0, 0, 0);
        acc1 = __builtin_amdgcn_mfma_f32_16x16x32_bf16(a, B1[ci], acc1, 0, 0, 0);
        acc2 = __builtin_amdgcn_mfma_f32_16x16x32_bf16(a, B2[ci], acc2, 0, 0, 0);
        acc3 = __builtin_amdgcn_mfma_f32_16x16x32_bf16(a, B3[ci], acc3, 0, 0, 0);
    }
    float bl0 = b_lin[0 * 16 + m], bl1 = b_lin[1 * 16 + m];
    float bl2 = b_lin[2 * 16 + m], bl3 = b_lin[3 * 16 + m];
    int row0 = row0b + wave * 16;
    #pragma unroll
    for (int j = 0; j < 4; ++j) {
        int row = row0 + kq * 4 + j;
        if (row < n) {
            float* orow = out + (size_t)row * 64;
            orow[0 * 16 + m] = acc0[j] + bl0;
            orow[1 * 16 + m] = acc1[j] + bl1;
            orow[2 * 16 + m] = acc2[j] + bl2;
            orow[3 * 16 + m] = acc3[j] + bl3;
        }
    }
}

extern "C" void kernel_launch(void* const* d_in, const int* in_sizes, int n_in,
                              void* d_out, int out_size, void* d_ws, size_t ws_size,
                              hipStream_t stream) {
    const float* x_label  = (const float*)d_in[0];
    const float* x_attr   = (const float*)d_in[1];
    const float* W_src_al = (const float*)d_in[7];
    const float* W_dst_al = (const float*)d_in[8];
    const float* a_src_al = (const float*)d_in[9];
    const float* a_dst_al = (const float*)d_in[10];
    const float* b_al     = (const float*)d_in[11];
    const float* W_lin    = (const float*)d_in[12];
    const float* b_lin    = (const float*)d_in[13];
    const int* edge_src   = (const int*)d_in[16];
    const int* edge_dst   = (const int*)d_in[17];

    const int D = 128;
    const int N_L = in_sizes[0] / D;
    const int N_A = in_sizes[1] / D;
    const int E   = in_sizes[16];

    const int nbDeg = (E + 255) / 256;
    const int nScan = (N_L + 1023) / 1024;
    const int nRL   = (N_L + 7) / 8;
    const int nRA   = (N_A + 7) / 8;
    const int nH    = (N_A + 31) / 32;

    // workspace layout (16B-aligned blocks)
    float* ws = (float*)d_ws;
    float* s_src = ws;                                  // N_A f
    float* s_dst = s_src + N_A;                         // N_L f
    float* wdst  = s_dst + N_L;                         // 128 f
    float* wsrc  = wdst + 128;                          // 128 f
    int*   deg    = (int*)(wsrc + 128);                 // N_L i   -- zeroed
    int*   cursor = deg + N_L;                          // N_L i   -- zeroed
    int*   bsum   = cursor + N_L;                       // 128 i
    int*   rowptr = bsum + 128;                         // N_L+4 i
    int2*  csr_pair = (int2*)(rowptr + N_L + 4);        // E int2 (offset even)
    unsigned short* Hb = (unsigned short*)(csr_pair + E);   // N_A*128 bf16
    unsigned short* Wb = Hb + (size_t)N_A * 128;            // 64*128 bf16

    float* out = (float*)d_out;

    // zero deg + cursor
    hipMemsetAsync(deg, 0, (size_t)2 * N_L * sizeof(int), stream);

    // K1: deg histogram | weight-vector projections | W_lin -> bf16^T
    k_pre<<<nbDeg + 1 + 32, 256, 0, stream>>>(edge_dst, deg, E, nbDeg,
                                              W_dst_al, a_dst_al, W_src_al, a_src_al,
                                              wdst, wsrc, W_lin, Wb);
    // K2: scanA (deg->bsum) | s_dst | s_src | Hb GEMM
    k_mid<<<nScan + nRL + nRA + nH, 256, 0, stream>>>(
        deg, bsum, nScan, N_L,
        x_label, wdst, s_dst, nRL, N_L,
        x_attr, wsrc, s_src, nRA, N_A,
        W_src_al, Hb);
    // K3/K4: finish rowptr scan
    k_scanB<<<1, 128, 0, stream>>>(bsum, nScan, rowptr, N_L, E);
    k_scanC<<<nScan, 256, 0, stream>>>(deg, bsum, rowptr, N_L);
    // K5: edge scatter into CSR with precomputed exp
    k_scatter<<<nbDeg, 256, 0, stream>>>(edge_src, edge_dst, s_src, s_dst,
                                         rowptr, cursor, csr_pair, E);
    // K6: fused gather + softmax-normalize + bias + relu + MFMA epilogue
    k_gatout<<<(N_L + 63) / 64, 256, 0, stream>>>(rowptr, csr_pair, Hb, b_al,
                                                  Wb, b_lin, out, N_L);
}

// Round 10
// 242.099 us; speedup vs baseline: 1.4608x; 1.0638x over previous
//
#include <hip/hip_runtime.h>
#include <math.h>

#define NEG_SLOPE 0.2f

typedef __attribute__((ext_vector_type(8))) short bf16x8;
typedef __attribute__((ext_vector_type(4))) float f32x4;

// float -> bf16 bits, round-to-nearest-even
__device__ __forceinline__ unsigned short f2bf(float f) {
    unsigned u = __float_as_uint(f);
    unsigned r = (u + 0x7FFFu + ((u >> 16) & 1u)) >> 16;
    return (unsigned short)r;
}

// unpack uint4 (8 bf16) -> accumulate a[0..7] += x * h[k]
__device__ __forceinline__ void acc8(float* a, uint4 u, float x) {
    a[0] += x * __uint_as_float(u.x << 16);
    a[1] += x * __uint_as_float(u.x & 0xFFFF0000u);
    a[2] += x * __uint_as_float(u.y << 16);
    a[3] += x * __uint_as_float(u.y & 0xFFFF0000u);
    a[4] += x * __uint_as_float(u.z << 16);
    a[5] += x * __uint_as_float(u.z & 0xFFFF0000u);
    a[6] += x * __uint_as_float(u.w << 16);
    a[7] += x * __uint_as_float(u.w & 0xFFFF0000u);
}

__device__ __forceinline__ unsigned pack2(unsigned short lo, unsigned short hi) {
    return (unsigned)lo | ((unsigned)hi << 16);
}

// ---------------- K_PRE: {deg histogram | wvec | wconv} ----------------
__global__ __launch_bounds__(256) void k_pre(
    const int* __restrict__ dst, int* __restrict__ deg, int E, int nbDeg,
    const float* __restrict__ Wd, const float* __restrict__ ad,
    const float* __restrict__ Ws, const float* __restrict__ as_,
    float* __restrict__ wdst, float* __restrict__ wsrc,
    const float* __restrict__ Wlin, unsigned short* __restrict__ Wb) {
    int b = blockIdx.x, t = threadIdx.x;
    if (b < nbDeg) {
        int i = b * 256 + t;
        if (i < E) atomicAdd(&deg[dst[i]], 1);
    } else if (b == nbDeg) {
        // wdst[d] = sum_h W_dst[d,h]*a_dst[h]; wsrc[d] = sum_h W_src[d,h]*a_src[h]
        const float* W = (t < 128) ? Wd : Ws;
        const float* a = (t < 128) ? ad : as_;
        int d = t & 127;
        float s = 0.f;
        #pragma unroll 8
        for (int h = 0; h < 128; ++h) s += W[d * 128 + h] * a[h];
        if (t < 128) wdst[d] = s; else wsrc[d] = s;
    } else {
        // Wb[col][k] = bf16(W_lin[k][col])
        int idx = (b - nbDeg - 1) * 256 + t;
        int col = idx >> 7, k = idx & 127;
        Wb[idx] = f2bf(Wlin[k * 64 + col]);
    }
}

// ---------------- role helpers for K_MID ----------------
// 32 rows/block, 8 rows/wave: 4 independent load+reduce chains per wave (ILP).
__device__ __forceinline__ void rowdot_role(const float* __restrict__ X,
                                            const float* __restrict__ v,
                                            float* __restrict__ out, int n,
                                            int vb, int t) {
    int wave = t >> 6, lane = t & 63;
    int half = lane >> 5, li = lane & 31;
    int row0 = (vb * 4 + wave) * 8 + half;     // rows row0 + 2*{0,1,2,3}
    const float4* X4 = (const float4*)X;
    const float4* V4 = (const float4*)v;
    float4 bv = V4[li];
    float p[4];
    #pragma unroll
    for (int k = 0; k < 4; ++k) {
        int row = row0 + 2 * k;
        p[k] = 0.f;
        if (row < n) {
            float4 x = X4[(size_t)row * 32 + li];
            p[k] = x.x * bv.x + x.y * bv.y + x.z * bv.z + x.w * bv.w;
        }
    }
    #pragma unroll
    for (int off = 16; off; off >>= 1) {
        #pragma unroll
        for (int k = 0; k < 4; ++k) p[k] += __shfl_xor(p[k], off);
    }
    if (li == 0) {
        #pragma unroll
        for (int k = 0; k < 4; ++k) {
            int row = row0 + 2 * k;
            if (row < n) out[row] = p[k];
        }
    }
}

__device__ __forceinline__ void hsrc_role(const float* __restrict__ X,
                                          const float* __restrict__ W,
                                          unsigned short* __restrict__ Hb,
                                          int nrows, int row0, int t,
                                          float* __restrict__ Xs /*32*128 lds*/) {
    #pragma unroll
    for (int i = 0; i < 16; ++i) {
        int idx = t + i * 256;
        int r = idx >> 7;
        Xs[r * 128 + (idx & 127)] = (row0 + r < nrows) ? X[(size_t)row0 * 128 + idx] : 0.f;
    }
    __syncthreads();
    int cg = t & 31, rg = t >> 5;
    float acc[4][4];
    #pragma unroll
    for (int i = 0; i < 4; ++i)
        #pragma unroll
        for (int j = 0; j < 4; ++j) acc[i][j] = 0.f;
    const float4* W4 = (const float4*)W;
    #pragma unroll 4
    for (int d = 0; d < 128; ++d) {
        float4 wv = W4[d * 32 + cg];
        float x0 = Xs[(rg * 4 + 0) * 128 + d], x1 = Xs[(rg * 4 + 1) * 128 + d];
        float x2 = Xs[(rg * 4 + 2) * 128 + d], x3 = Xs[(rg * 4 + 3) * 128 + d];
        acc[0][0] += x0 * wv.x; acc[0][1] += x0 * wv.y; acc[0][2] += x0 * wv.z; acc[0][3] += x0 * wv.w;
        acc[1][0] += x1 * wv.x; acc[1][1] += x1 * wv.y; acc[1][2] += x1 * wv.z; acc[1][3] += x1 * wv.w;
        acc[2][0] += x2 * wv.x; acc[2][1] += x2 * wv.y; acc[2][2] += x2 * wv.z; acc[2][3] += x2 * wv.w;
        acc[3][0] += x3 * wv.x; acc[3][1] += x3 * wv.y; acc[3][2] += x3 * wv.z; acc[3][3] += x3 * wv.w;
    }
    #pragma unroll
    for (int i = 0; i < 4; ++i) {
        int gr = row0 + rg * 4 + i;
        if (gr < nrows) {
            ushort4 o;
            o.x = f2bf(acc[i][0]); o.y = f2bf(acc[i][1]);
            o.z = f2bf(acc[i][2]); o.w = f2bf(acc[i][3]);
            *(ushort4*)&Hb[(size_t)gr * 128 + cg * 4] = o;
        }
    }
}

// Fused scan role: block vb handles deg[vb*1024 .. vb*1024+1024) -> rowptr.
// Global offset computed by redundantly summing deg[0..vb*1024) (L2-resident,
// no cross-block dependency -- G16-safe).
__device__ __forceinline__ void scan_role(const int* __restrict__ deg,
                                          int* __restrict__ rowptr, int n, int E,
                                          int vb, int t, int* __restrict__ sd) {
    // phase A: offset = sum deg[0 .. vb*1024)
    const int4* deg4 = (const int4*)deg;
    int nq = vb * 256;
    int s = 0;
    for (int i = t; i < nq; i += 256) {
        int4 v = deg4[i];
        s += (v.x + v.y) + (v.z + v.w);
    }
    sd[t] = s;
    __syncthreads();
    for (int off = 128; off; off >>= 1) {
        if (t < off) sd[t] += sd[t + off];
        __syncthreads();
    }
    int offset = sd[0];
    __syncthreads();
    // phase B: local exclusive scan of this chunk
    int base = vb * 1024 + t * 4;
    int d[4]; int tsum = 0;
    #pragma unroll
    for (int i = 0; i < 4; ++i) { d[i] = (base + i < n) ? deg[base + i] : 0; tsum += d[i]; }
    sd[t] = tsum;
    __syncthreads();
    for (int off = 1; off < 256; off <<= 1) {
        int v = (t >= off) ? sd[t - off] : 0;
        __syncthreads();
        sd[t] += v;
        __syncthreads();
    }
    int excl = sd[t] - tsum + offset;
    #pragma unroll
    for (int i = 0; i < 4; ++i) {
        if (base + i < n) rowptr[base + i] = excl;
        excl += d[i];
    }
    if (vb == 0 && t == 0) rowptr[n] = E;
}

// ---------------- K_MID: {hsrc | rowdot(xL) | rowdot(xA) | full scan} ----------------
// hsrc first (heaviest blocks dispatch earliest -> no serial tail).
__global__ __launch_bounds__(256) void k_mid(
    const int* __restrict__ deg, int* __restrict__ rowptr, int nScan, int n, int E,
    const float* __restrict__ xL, const float* __restrict__ wdst,
    float* __restrict__ sdst, int nRL, int NL,
    const float* __restrict__ xA, const float* __restrict__ wsrc,
    float* __restrict__ ssrc, int nRA, int NA,
    const float* __restrict__ Wsrc, unsigned short* __restrict__ Hb, int nH) {
    __shared__ float smemf[32 * 128];
    int b = blockIdx.x, t = threadIdx.x;
    if (b < nH) {
        hsrc_role(xA, Wsrc, Hb, NA, b * 32, t, smemf);
    } else if (b < nH + nRL) {
        rowdot_role(xL, wdst, sdst, NL, b - nH, t);
    } else if (b < nH + nRL + nRA) {
        rowdot_role(xA, wsrc, ssrc, NA, b - nH - nRL, t);
    } else {
        scan_role(deg, rowptr, n, E, b - nH - nRL - nRA, t, (int*)smemf);
    }
}

// ---------------- K_SCATTER: ex = exp(leaky(e)); place (src,ex) in CSR slot ----------------
__global__ void k_scatter(const int* __restrict__ src, const int* __restrict__ dst,
                          const float* __restrict__ ssrc, const float* __restrict__ sdst,
                          const int* __restrict__ rowptr, int* __restrict__ cursor,
                          int2* __restrict__ csr_pair, int E) {
    int i = blockIdx.x * blockDim.x + threadIdx.x;
    if (i >= E) return;
    int s = src[i], d = dst[i];
    float e = ssrc[s] + sdst[d];
    e = e > 0.f ? e : NEG_SLOPE * e;
    float ex = __expf(e);
    int pos = rowptr[d] + atomicAdd(&cursor[d], 1);
    csr_pair[pos] = make_int2(s, __float_as_int(ex));
}

// ---------------- K_GATOUT: gather -> G tile in LDS -> MFMA epilogue ----------------
// Block = 4 waves = 64 dst rows. Phase 1: each wave gathers 4 rows x 4 passes
// (16 lanes/row, one 16B bf16x8 load/edge), writes swizzled G to LDS.
// Phase 2: wave w MFMAs rows [w*16, w*16+16) x 64 cols, K=128, A from LDS.
__global__ __launch_bounds__(256) void k_gatout(
    const int* __restrict__ rowptr, const int2* __restrict__ csr_pair,
    const unsigned short* __restrict__ Hb, const float* __restrict__ b_al,
    const unsigned short* __restrict__ Wb, const float* __restrict__ b_lin,
    float* __restrict__ out, int n) {
    __shared__ unsigned short Gs[64 * 128];   // 16 KB, 16B slots XOR-swizzled
    int t = threadIdx.x;
    int wave = t >> 6, lane = t & 63;
    int grp = lane >> 4, gl = lane & 15;
    const uint4* H16 = (const uint4*)Hb;
    int row0b = blockIdx.x * 64;
    const float4* B4 = (const float4*)b_al;
    float4 bA = B4[gl * 2], bB = B4[gl * 2 + 1];

    #pragma unroll
    for (int rr = 0; rr < 4; ++rr) {
        int rl = wave * 16 + rr * 4 + grp;     // local row 0..63
        int row = row0b + rl;
        uint4 gpack = make_uint4(0u, 0u, 0u, 0u);
        if (row < n) {
            int beg = rowptr[row], end = rowptr[row + 1];
            float a[8];
            #pragma unroll
            for (int k = 0; k < 8; ++k) a[k] = 0.f;
            float denom = 0.f;
            int j = beg;
            for (; j + 4 <= end; j += 4) {
                int2 p0 = csr_pair[j], p1 = csr_pair[j + 1];
                int2 p2 = csr_pair[j + 2], p3 = csr_pair[j + 3];
                float x0 = __int_as_float(p0.y), x1 = __int_as_float(p1.y);
                float x2 = __int_as_float(p2.y), x3 = __int_as_float(p3.y);
                uint4 u0 = H16[(size_t)p0.x * 16 + gl];
                uint4 u1 = H16[(size_t)p1.x * 16 + gl];
                uint4 u2 = H16[(size_t)p2.x * 16 + gl];
                uint4 u3 = H16[(size_t)p3.x * 16 + gl];
                denom += (x0 + x1) + (x2 + x3);
                acc8(a, u0, x0); acc8(a, u1, x1); acc8(a, u2, x2); acc8(a, u3, x3);
            }
            for (; j + 2 <= end; j += 2) {
                int2 p0 = csr_pair[j], p1 = csr_pair[j + 1];
                float x0 = __int_as_float(p0.y), x1 = __int_as_float(p1.y);
                uint4 u0 = H16[(size_t)p0.x * 16 + gl];
                uint4 u1 = H16[(size_t)p1.x * 16 + gl];
                denom += x0 + x1;
                acc8(a, u0, x0); acc8(a, u1, x1);
            }
            if (j < end) {
                int2 p0 = csr_pair[j];
                float x0 = __int_as_float(p0.y);
                uint4 u0 = H16[(size_t)p0.x * 16 + gl];
                denom += x0;
                acc8(a, u0, x0);
            }
            float inv = denom > 0.f ? 1.f / denom : 0.f;
            unsigned short g0 = f2bf(fmaxf(a[0] * inv + bA.x, 0.f));
            unsigned short g1 = f2bf(fmaxf(a[1] * inv + bA.y, 0.f));
            unsigned short g2 = f2bf(fmaxf(a[2] * inv + bA.z, 0.f));
            unsigned short g3 = f2bf(fmaxf(a[3] * inv + bA.w, 0.f));
            unsigned short g4 = f2bf(fmaxf(a[4] * inv + bB.x, 0.f));
            unsigned short g5 = f2bf(fmaxf(a[5] * inv + bB.y, 0.f));
            unsigned short g6 = f2bf(fmaxf(a[6] * inv + bB.z, 0.f));
            unsigned short g7 = f2bf(fmaxf(a[7] * inv + bB.w, 0.f));
            gpack = make_uint4(pack2(g0, g1), pack2(g2, g3), pack2(g4, g5), pack2(g6, g7));
        }
        int slot = gl ^ (rl & 15);             // swizzle: conflict-free phase-2 reads
        *(uint4*)&Gs[rl * 128 + slot * 8] = gpack;
    }
    __syncthreads();

    // phase 2: MFMA. A: m=lane&15, k-chunk ci=s*4+kq; B: n=lane&15;
    // D: col=lane&15, row=(lane>>4)*4+reg (m89-verified layouts).
    int m = lane & 15, kq = lane >> 4;
    int rl = wave * 16 + m;
    f32x4 acc0 = {0.f, 0.f, 0.f, 0.f};
    f32x4 acc1 = {0.f, 0.f, 0.f, 0.f};
    f32x4 acc2 = {0.f, 0.f, 0.f, 0.f};
    f32x4 acc3 = {0.f, 0.f, 0.f, 0.f};
    const bf16x8* B0 = (const bf16x8*)(Wb + (size_t)(0 * 16 + m) * 128);
    const bf16x8* B1 = (const bf16x8*)(Wb + (size_t)(1 * 16 + m) * 128);
    const bf16x8* B2 = (const bf16x8*)(Wb + (size_t)(2 * 16 + m) * 128);
    const bf16x8* B3 = (const bf16x8*)(Wb + (size_t)(3 * 16 + m) * 128);
    #pragma unroll
    for (int s = 0; s < 4; ++s) {
        int ci = s * 4 + kq;
        int slot = ci ^ m;                     // rl&15 == m
        bf16x8 a = *(const bf16x8*)&Gs[rl * 128 + slot * 8];
        acc0 = __builtin_amdgcn_mfma_f32_16x16x32_bf16(a, B0[ci], acc0, 0, 0, 0);
        acc1 = __builtin_amdgcn_mfma_f32_16x16x32_bf16(a, B1[ci], acc1, 0, 0, 0);
        acc2 = __builtin_amdgcn_mfma_f32_16x16x32_bf16(a, B2[ci], acc2, 0, 0, 0);
        acc3 = __builtin_amdgcn_mfma_f32_16x16x32_bf16(a, B3[ci], acc3, 0, 0, 0);
    }
    float bl0 = b_lin[0 * 16 + m], bl1 = b_lin[1 * 16 + m];
    float bl2 = b_lin[2 * 16 + m], bl3 = b_lin[3 * 16 + m];
    int row0 = row0b + wave * 16;
    #pragma unroll
    for (int j = 0; j < 4; ++j) {
        int row = row0 + kq * 4 + j;
        if (row < n) {
            float* orow = out + (size_t)row * 64;
            orow[0 * 16 + m] = acc0[j] + bl0;
            orow[1 * 16 + m] = acc1[j] + bl1;
            orow[2 * 16 + m] = acc2[j] + bl2;
            orow[3 * 16 + m] = acc3[j] + bl3;
        }
    }
}

extern "C" void kernel_launch(void* const* d_in, const int* in_sizes, int n_in,
                              void* d_out, int out_size, void* d_ws, size_t ws_size,
                              hipStream_t stream) {
    const float* x_label  = (const float*)d_in[0];
    const float* x_attr   = (const float*)d_in[1];
    const float* W_src_al = (const float*)d_in[7];
    const float* W_dst_al = (const float*)d_in[8];
    const float* a_src_al = (const float*)d_in[9];
    const float* a_dst_al = (const float*)d_in[10];
    const float* b_al     = (const float*)d_in[11];
    const float* W_lin    = (const float*)d_in[12];
    const float* b_lin    = (const float*)d_in[13];
    const int* edge_src   = (const int*)d_in[16];
    const int* edge_dst   = (const int*)d_in[17];

    const int D = 128;
    const int N_L = in_sizes[0] / D;
    const int N_A = in_sizes[1] / D;
    const int E   = in_sizes[16];

    const int nbDeg = (E + 255) / 256;
    const int nScan = (N_L + 1023) / 1024;
    const int nRL   = (N_L + 31) / 32;
    const int nRA   = (N_A + 31) / 32;
    const int nH    = (N_A + 31) / 32;

    // workspace layout (16B-aligned blocks)
    float* ws = (float*)d_ws;
    float* s_src = ws;                                  // N_A f
    float* s_dst = s_src + N_A;                         // N_L f
    float* wdst  = s_dst + N_L;                         // 128 f
    float* wsrc  = wdst + 128;                          // 128 f
    int*   deg    = (int*)(wsrc + 128);                 // N_L i   -- zeroed
    int*   cursor = deg + N_L;                          // N_L i   -- zeroed
    int*   rowptr = cursor + N_L;                       // N_L+4 i
    int2*  csr_pair = (int2*)(rowptr + N_L + 4);        // E int2 (offset even)
    unsigned short* Hb = (unsigned short*)(csr_pair + E);   // N_A*128 bf16
    unsigned short* Wb = Hb + (size_t)N_A * 128;            // 64*128 bf16

    float* out = (float*)d_out;

    // zero deg + cursor
    hipMemsetAsync(deg, 0, (size_t)2 * N_L * sizeof(int), stream);

    // K1: deg histogram | weight-vector projections | W_lin -> bf16^T
    k_pre<<<nbDeg + 1 + 32, 256, 0, stream>>>(edge_dst, deg, E, nbDeg,
                                              W_dst_al, a_dst_al, W_src_al, a_src_al,
                                              wdst, wsrc, W_lin, Wb);
    // K2: hsrc GEMM | s_dst | s_src | full rowptr scan
    k_mid<<<nH + nRL + nRA + nScan, 256, 0, stream>>>(
        deg, rowptr, nScan, N_L, E,
        x_label, wdst, s_dst, nRL, N_L,
        x_attr, wsrc, s_src, nRA, N_A,
        W_src_al, Hb, nH);
    // K3: edge scatter into CSR with precomputed exp
    k_scatter<<<nbDeg, 256, 0, stream>>>(edge_src, edge_dst, s_src, s_dst,
                                         rowptr, cursor, csr_pair, E);
    // K4: fused gather + softmax-normalize + bias + relu + MFMA epilogue
    k_gatout<<<(N_L + 63) / 64, 256, 0, stream>>>(rowptr, csr_pair, Hb, b_al,
                                                  Wb, b_lin, out, N_L);
}